// Round 1
// baseline (256.752 us; speedup 1.0000x reference)
//
#include <hip/hip_runtime.h>

// SFM recurrent model: B=2048, T=60, D=6, H=64, F=10, O=1.
// Layout: 1024 blocks x 128 threads (2 waves). Block handles 2 batches.
// wave 0: gates (i, ste) for both batches; owns batch 0 state/pointwise.
// wave 1: gates (c, o)  for both batches; owns batch 1 state/pointwise.
// Lane = h index (0..63). U matrices live in VGPRs (64+64 per wave).

#define BB 2048
#define TT 60
#define DD 6
#define HH 64
#define FF 10

__device__ __forceinline__ float hsig_f(float v) {
    return fminf(fmaxf(fmaf(v, 0.16666666666666666f, 0.5f), 0.0f), 1.0f);
}

__device__ __forceinline__ float tanh_f(float x) {
    // tanh(x) = (e^{2x}-1)/(e^{2x}+1); clamp avoids exp overflow, tanh saturated anyway
    float xc = fminf(fmaxf(x, -12.0f), 12.0f);
    float e  = __builtin_amdgcn_exp2f(xc * 2.8853900817779268f); // 2*log2(e)
    return (e - 1.0f) * __builtin_amdgcn_rcpf(e + 1.0f);
}

__device__ __forceinline__ float rdlane(float v, int l) {
    return __int_as_float(__builtin_amdgcn_readlane(__float_as_int(v), l));
}

__device__ __forceinline__ float uni(float v) {
    return __int_as_float(__builtin_amdgcn_readfirstlane(__float_as_int(v)));
}

__global__ __launch_bounds__(128, 2) void sfm_kernel(
    const float* __restrict__ x,
    const float* __restrict__ W_i,  const float* __restrict__ U_i,  const float* __restrict__ b_i,
    const float* __restrict__ W_ste,const float* __restrict__ U_ste,const float* __restrict__ b_ste,
    const float* __restrict__ W_fre,const float* __restrict__ U_fre,const float* __restrict__ b_fre,
    const float* __restrict__ W_c,  const float* __restrict__ U_c,  const float* __restrict__ b_c,
    const float* __restrict__ W_o,  const float* __restrict__ U_o,  const float* __restrict__ b_o,
    const float* __restrict__ U_a,  const float* __restrict__ b_a,
    const float* __restrict__ W_p,  const float* __restrict__ b_p,
    float* __restrict__ out)
{
    const int lane = threadIdx.x & 63;
    const int wave = threadIdx.x >> 6;   // 0 or 1
    const int b0   = blockIdx.x * 2;

    __shared__ float h_s[2][HH];    // current h per batch
    __shared__ float zx[4][HH];     // [0]=i(b1) [1]=ste(b1) [2]=c(b0) [3]=o(b0)
    __shared__ float fp_s[2][64];   // fre partial sums
    __shared__ float fre_s[2][16];  // activated fre per batch

    // ---- per-wave gate weights into registers ----
    const float* Wa = (wave == 0) ? W_i   : W_c;
    const float* Ua = (wave == 0) ? U_i   : U_c;
    const float* ba = (wave == 0) ? b_i   : b_c;
    const float* Wb = (wave == 0) ? W_ste : W_o;
    const float* Ub = (wave == 0) ? U_ste : U_o;
    const float* bb = (wave == 0) ? b_ste : b_o;

    float uA[HH], uB[HH];
    #pragma unroll
    for (int j = 0; j < HH; ++j) { uA[j] = Ua[j * HH + lane]; uB[j] = Ub[j * HH + lane]; }
    float wA[DD], wB[DD];
    #pragma unroll
    for (int d = 0; d < DD; ++d) { wA[d] = Wa[d * HH + lane]; wB[d] = Wb[d * HH + lane]; }
    const float bAv = ba[lane];
    const float bBv = bb[lane];
    const float bav = b_a[lane];
    const float wpv = W_p[lane];
    const float bpv = uni(b_p[0]);

    // U_a column -> SGPRs (uniform)
    float uav[FF];
    #pragma unroll
    for (int f = 0; f < FF; ++f) uav[f] = uni(U_a[f]);

    // ---- fre partial-sum lane mapping: lane = f*6 + jc (lanes 0..59) ----
    const int  f_idx = lane / 6;
    const int  jc    = lane - f_idx * 6;
    const bool fre_active = (lane < 60);
    const int  j0   = jc * 11 - ((jc > 4) ? 1 : 0);   // chunks 11,11,11,11,10,10
    const int  jlen = (jc < 4) ? 11 : 10;
    float ufre[11];
    #pragma unroll
    for (int i = 0; i < 11; ++i)
        ufre[i] = (fre_active && i < jlen) ? U_fre[(j0 + i) * FF + f_idx] : 0.0f;

    float wfre[DD];
    float bfre = 0.0f;
    #pragma unroll
    for (int d = 0; d < DD; ++d) wfre[d] = 0.0f;
    if (lane < FF) {
        #pragma unroll
        for (int d = 0; d < DD; ++d) wfre[d] = W_fre[d * FF + lane];
        bfre = b_fre[lane];
    }

    // ---- rotation constants: cos/sin(2*pi*f/10), exact ----
    const float CB[FF] = { 1.0f,  0.8090169943749475f,  0.30901699437494745f,
                          -0.30901699437494745f, -0.8090169943749475f, -1.0f,
                          -0.8090169943749475f, -0.30901699437494745f,
                           0.30901699437494745f,  0.8090169943749475f };
    const float SB[FF] = { 0.0f,  0.5877852522924731f,  0.9510565162951535f,
                           0.9510565162951535f,  0.5877852522924731f,  0.0f,
                          -0.5877852522924731f, -0.9510565162951535f,
                          -0.9510565162951535f, -0.5877852522924731f };

    // ---- state ----
    float Sre[FF], Sim[FF], cs[FF], sn[FF];
    #pragma unroll
    for (int f = 0; f < FF; ++f) { Sre[f] = 0.0f; Sim[f] = 0.0f; cs[f] = CB[f]; sn[f] = SB[f]; }
    float hself = 0.0f;

    h_s[wave][lane] = 0.0f;

    const float* xp0 = x + (size_t)b0 * TT * DD;
    const float* xp1 = xp0 + TT * DD;

    int sm = 0; // step mod 10
    for (int s = 0; s < TT; ++s) {
        __syncthreads();   // barrier 1: h_s (and zx reuse) coherent

        // ---- phase A: gate pre-activations ----
        float xs0[DD], xs1[DD];
        #pragma unroll
        for (int d = 0; d < DD; ++d) {
            xs0[d] = uni(xp0[s * DD + d]);
            xs1[d] = uni(xp1[s * DD + d]);
        }

        float hreg0 = h_s[0][lane];
        float hreg1 = h_s[1][lane];

        float zA0 = bAv, zB0 = bBv, zA1 = bAv, zB1 = bBv;
        #pragma unroll
        for (int d = 0; d < DD; ++d) {
            zA0 = fmaf(xs0[d], wA[d], zA0);
            zB0 = fmaf(xs0[d], wB[d], zB0);
            zA1 = fmaf(xs1[d], wA[d], zA1);
            zB1 = fmaf(xs1[d], wB[d], zB1);
        }
        #pragma unroll
        for (int j = 0; j < HH; ++j) {
            float h0 = rdlane(hreg0, j);
            float h1 = rdlane(hreg1, j);
            zA0 = fmaf(h0, uA[j], zA0);
            zB0 = fmaf(h0, uB[j], zB0);
            zA1 = fmaf(h1, uA[j], zA1);
            zB1 = fmaf(h1, uB[j], zB1);
        }

        if (wave == 0) { zx[0][lane] = zA1; zx[1][lane] = zB1; }
        else           { zx[2][lane] = zA0; zx[3][lane] = zB0; }

        // ---- fre for own batch (intra-wave) ----
        float part = 0.0f;
        #pragma unroll
        for (int i = 0; i < 11; ++i) {
            int jj = j0 + i; jj = (jj > 63) ? 63 : jj;
            part = fmaf(h_s[wave][jj], ufre[i], part);
        }
        fp_s[wave][lane] = part;
        if (lane < FF) {
            float acc = bfre;
            #pragma unroll
            for (int q = 0; q < 6; ++q) acc += fp_s[wave][lane * 6 + q];
            #pragma unroll
            for (int d = 0; d < DD; ++d)
                acc = fmaf((wave == 0) ? xs0[d] : xs1[d], wfre[d], acc);
            fre_s[wave][lane] = hsig_f(acc);
        }

        __syncthreads();   // barrier 2: zx coherent

        // ---- phase B: pointwise update for own batch ----
        float zi, zst, zc, zo;
        if (wave == 0) { zi = zA0;        zst = zB0;        zc = zx[2][lane]; zo = zx[3][lane]; }
        else           { zi = zx[0][lane]; zst = zx[1][lane]; zc = zA1;       zo = zB1; }

        float iv  = hsig_f(zi);
        float stv = hsig_f(zst);
        float ov  = hsig_f(zo);
        float cv  = iv * tanh_f(zc);

        if (sm == 0) {
            #pragma unroll
            for (int f = 0; f < FF; ++f) { cs[f] = CB[f]; sn[f] = SB[f]; }
        }

        float aacc = bav;
        #pragma unroll
        for (int f = 0; f < FF; ++f) {
            float frf = fre_s[wave][f];
            float fc  = stv * frf;
            Sre[f] = fmaf(cv, cs[f], fc * Sre[f]);
            Sim[f] = fmaf(cv, sn[f], fc * Sim[f]);
            float A = fmaf(Sim[f], Sim[f], Sre[f] * Sre[f]);
            aacc = fmaf(A, uav[f], aacc);
        }
        float av = tanh_f(aacc);
        hself = ov * av;
        h_s[wave][lane] = hself;

        // rotate (cs,sn) by 2*pi*f/10 for next step
        #pragma unroll
        for (int f = 0; f < FF; ++f) {
            float c0 = cs[f];
            cs[f] = fmaf(c0, CB[f], -(sn[f] * SB[f]));
            sn[f] = fmaf(c0, SB[f],   sn[f] * CB[f]);
        }
        if (++sm == 10) sm = 0;
    }

    // ---- output: out[b] = sum_k h[k]*W_p[k] + b_p ----
    float val = hself * wpv;
    #pragma unroll
    for (int off = 32; off > 0; off >>= 1) val += __shfl_xor(val, off, 64);
    if (lane == 0) out[b0 + wave] = val + bpv;
}

extern "C" void kernel_launch(void* const* d_in, const int* in_sizes, int n_in,
                              void* d_out, int out_size, void* d_ws, size_t ws_size,
                              hipStream_t stream) {
    (void)in_sizes; (void)n_in; (void)d_ws; (void)ws_size; (void)out_size;
    const float* x     = (const float*)d_in[0];
    const float* W_i   = (const float*)d_in[1];
    const float* U_i   = (const float*)d_in[2];
    const float* b_i   = (const float*)d_in[3];
    const float* W_ste = (const float*)d_in[4];
    const float* U_ste = (const float*)d_in[5];
    const float* b_ste = (const float*)d_in[6];
    const float* W_fre = (const float*)d_in[7];
    const float* U_fre = (const float*)d_in[8];
    const float* b_fre = (const float*)d_in[9];
    const float* W_c   = (const float*)d_in[10];
    const float* U_c   = (const float*)d_in[11];
    const float* b_c   = (const float*)d_in[12];
    const float* W_o   = (const float*)d_in[13];
    const float* U_o   = (const float*)d_in[14];
    const float* b_o   = (const float*)d_in[15];
    const float* U_a   = (const float*)d_in[16];
    const float* b_a   = (const float*)d_in[17];
    const float* W_p   = (const float*)d_in[18];
    const float* b_p   = (const float*)d_in[19];

    sfm_kernel<<<BB / 2, 128, 0, stream>>>(
        x, W_i, U_i, b_i, W_ste, U_ste, b_ste, W_fre, U_fre, b_fre,
        W_c, U_c, b_c, W_o, U_o, b_o, U_a, b_a, W_p, b_p, (float*)d_out);
}